// Round 6
// baseline (8496.381 us; speedup 1.0000x reference)
//
#include <hip/hip_runtime.h>
#include <hip/hip_fp16.h>
#include <cstdint>
#include <cstddef>
#include <cstring>

#define T_SEQ 512
#define NB 32

__device__ __forceinline__ uint32_t agent_load_u32(const uint32_t* p) {
    return __hip_atomic_load(p, __ATOMIC_RELAXED, __HIP_MEMORY_SCOPE_AGENT);
}
__device__ __forceinline__ void agent_store_u32(uint32_t* p, uint32_t v) {
    __hip_atomic_store(p, v, __ATOMIC_RELAXED, __HIP_MEMORY_SCOPE_AGENT);
}
__device__ __forceinline__ float hbits2f(unsigned short us) {
    __half h; __builtin_memcpy(&h, &us, 2); return __half2float(h);
}

// =====================================================================
// rec512_both: layers 0 AND 1 in ONE workgroup, wave-split + lockstep.
//   256 blocks (b = bid&31, s = bid>>5), 1024 threads:
//     tid   0..511 (waves 0-7) : layer-0 slice (b,s)
//     tid 512..1023 (waves 8-15): layer-1 slice (b,s), lag 2 (t1 = tt-2)
//
// REGISTER ALLOCATION (r1/r5 lesson): launch_bounds' 2nd arg is only a
// MINIMUM waves/EU — it bounds VGPR from above but the LLVM occupancy
// heuristic still AIMS at 8 waves/EU (64 VGPR) and remats the weight
// arrays to get there (r5: VGPR=64, FETCH=11.2 GB/dispatch, 7.9 ms).
// amdgpu_waves_per_eu(4,4) pins BOTH bounds: a 16-wave workgroup can
// only ever reach 4 waves/EU, so max=4 removes any incentive to shrink
// below the 128-VGPR budget. Natural need ~105 -> fits, no remat.
//
// POISON ROBUSTNESS (r4 root cause): harness re-poisons d_ws; hpk polls
// are EQUALITY against small tags (poison-safe), but prog0's >= poll is
// not -> kernel_launch memsets hpk0|hpk1|prog0 (263168 B) to 0 first.
//
// Deadlock-freedom: every phase-A poll depends only on OTHER blocks
// having COMPLETED iteration <= tt-1 (hpk0 tag tt, prog0 >= tt, hpk1
// tag tt-2 are all produced at end of iteration tt-1); iteration 0 has
// no polls -> induction. Initial r0(0) staging is folded into tt=1.
// Lockstep backpressure makes tag-slot reuse safe (see r4 notes).
// =====================================================================
__global__ __launch_bounds__(1024)
__attribute__((amdgpu_waves_per_eu(4, 4)))
void rec512_both(
    const float* __restrict__ x,
    const float* __restrict__ Wih0, const float* __restrict__ Whh0,
    const float* __restrict__ bih0, const float* __restrict__ bhh0,
    const float* __restrict__ Wih1, const float* __restrict__ Whh1,
    const float* __restrict__ bih1, const float* __restrict__ bhh1,
    uint32_t* __restrict__ r0w,        // [NB][T][256] relu0 fp16 pairs
    unsigned short* __restrict__ r1h,  // [NB][T][512] fp16 bits
    uint32_t* __restrict__ hpk0, uint32_t* __restrict__ hpk1,
    uint32_t* __restrict__ prog0)      // [NB][8] layer-0 step counters
{
    __shared__ float hbuf0[2][512];
    __shared__ float hbuf1[2][512];
    __shared__ float rbuf[2][512];     // relu0 staging for l1
    __shared__ float xbuf[2][128];     // x staging for l0
    __shared__ float part0[8][64];
    __shared__ float part1[8][64];

    const int tid  = threadIdx.x;
    const int b    = blockIdx.x & 31;
    const int s    = blockIdx.x >> 5;  // 0..7
    const bool isL1 = tid >= 512;
    const int lane = tid & 511;        // 0..511: poll-row within layer
    const int jl   = lane & 63;
    const int kq   = lane >> 6;        // 0..7, wave-uniform
    const int row  = (s << 6) + jl;
    const bool own = (kq == s);

    // ---- weights to VGPRs (fp16 pairs) ----
    // l0: wA[0..31] = Whh0 row, 64 k  |  wB[0..7] = Wih0 row, 16 k
    // l1: wA[0..31] = Wih1 row, 64 k  |  wB[0..31] = Whh1 row, 64 k
    __half2 wA[32], wB[32];
    if (!isL1) {
        const float4* p4 = (const float4*)(Whh0 + (size_t)row * 512 + (kq << 6));
#pragma unroll
        for (int i = 0; i < 16; i++) {
            const float4 v = p4[i];
            wA[2 * i]     = __floats2half2_rn(v.x, v.y);
            wA[2 * i + 1] = __floats2half2_rn(v.z, v.w);
        }
        const float4* q4 = (const float4*)(Wih0 + (size_t)row * 128 + (kq << 4));
#pragma unroll
        for (int i = 0; i < 4; i++) {
            const float4 v = q4[i];
            wB[2 * i]     = __floats2half2_rn(v.x, v.y);
            wB[2 * i + 1] = __floats2half2_rn(v.z, v.w);
        }
    } else {
        const float4* p4 = (const float4*)(Wih1 + (size_t)row * 512 + (kq << 6));
#pragma unroll
        for (int i = 0; i < 16; i++) {
            const float4 v = p4[i];
            wA[2 * i]     = __floats2half2_rn(v.x, v.y);
            wA[2 * i + 1] = __floats2half2_rn(v.z, v.w);
        }
        p4 = (const float4*)(Whh1 + (size_t)row * 512 + (kq << 6));
#pragma unroll
        for (int i = 0; i < 16; i++) {
            const float4 v = p4[i];
            wB[2 * i]     = __floats2half2_rn(v.x, v.y);
            wB[2 * i + 1] = __floats2half2_rn(v.z, v.w);
        }
    }
    float bias = 0.f;
    if (tid < 64) {
        const int r = (s << 6) + tid; bias = bih0[r] + bhh0[r];
    } else if (tid >= 512 && tid < 576) {
        const int r = (s << 6) + (tid - 512); bias = bih1[r] + bhh1[r];
    }

    const float* x_b = x + (size_t)b * (T_SEQ * 128);
    uint32_t* r0_b = r0w + (size_t)b * (T_SEQ * 256);
    unsigned short* r1_b = r1h + (size_t)b * (T_SEQ * 512);
    uint32_t* hp0_b = hpk0 + (b << 10);
    uint32_t* hp1_b = hpk1 + (b << 10);
    uint32_t* pr_b  = prog0 + (b << 3);

    if (tid < 128) xbuf[0][tid] = x_b[tid];
    __syncthreads();

    for (int tt = 0; tt < T_SEQ + 2; tt++) {
        const int t1 = tt - 2;
        // ---------------- phase A: polls + global prefetch ----------------
        float xn = 0.f;
        uint32_t rn = 0;
        if (!isL1) {
            if (tid < 128 && tt + 1 < T_SEQ) xn = x_b[(tt + 1) * 128 + tid];
            if (tt > 0 && tt < T_SEQ && !own) {
                const uint32_t wtag = (uint32_t)tt;
                uint32_t* sp = hp0_b + ((tt & 1) << 9) + lane;
                uint32_t v;
                do { v = agent_load_u32(sp); } while ((v & 0xffffu) != wtag);
                hbuf0[tt & 1][lane] = hbits2f((unsigned short)(v >> 16));
            }
        } else {
            // stagers: lanes 256..511 fetch r0(tt-1) for l1's step tt-1
            if (lane >= 256 && tt >= 1 && tt <= T_SEQ) {
                const int wl = lane - 256;   // 0..255
                const uint32_t need = (uint32_t)tt;
                const uint32_t* pp = pr_b + (wl >> 5);
                uint32_t pv;
                do { pv = agent_load_u32(pp); } while (pv < need);
                asm volatile("" ::: "memory");
                rn = agent_load_u32(r0_b + (size_t)(tt - 1) * 256 + wl);
            }
            if (t1 > 0 && t1 < T_SEQ && !own) {
                const uint32_t wtag = (uint32_t)t1;
                uint32_t* sp = hp1_b + ((t1 & 1) << 9) + lane;
                uint32_t v;
                do { v = agent_load_u32(sp); } while ((v & 0xffffu) != wtag);
                hbuf1[t1 & 1][lane] = hbits2f((unsigned short)(v >> 16));
            }
        }
        __syncthreads();   // B1
        // ---------------- post-B1 LDS writes ----------------
        if (!isL1) {
            if (tid < 128 && tt + 1 < T_SEQ) xbuf[(tt + 1) & 1][tid] = xn;
        } else if (lane >= 256 && tt >= 1 && tt <= T_SEQ) {
            const int wl = lane - 256;
            rbuf[(tt - 1) & 1][2 * wl]     = hbits2f((unsigned short)(rn & 0xffffu));
            rbuf[(tt - 1) & 1][2 * wl + 1] = hbits2f((unsigned short)(rn >> 16));
        }
        // ---------------- FMA ----------------
        if (!isL1) {
            if (tt < T_SEQ) {
                float a0 = 0.f, a1 = 0.f, a2 = 0.f, a3 = 0.f;
                if (tt > 0) {
                    const float4* hq = (const float4*)(&hbuf0[tt & 1][kq << 6]);
#pragma unroll
                    for (int i = 0; i < 16; i++) {
                        const float4 h4 = hq[i];
                        a0 = fmaf(__low2float(wA[2 * i]),      h4.x, a0);
                        a1 = fmaf(__high2float(wA[2 * i]),     h4.y, a1);
                        a2 = fmaf(__low2float(wA[2 * i + 1]),  h4.z, a2);
                        a3 = fmaf(__high2float(wA[2 * i + 1]), h4.w, a3);
                    }
                }
                {
                    const float4* xq = (const float4*)(&xbuf[tt & 1][kq << 4]);
#pragma unroll
                    for (int i = 0; i < 4; i++) {
                        const float4 x4 = xq[i];
                        a0 = fmaf(__low2float(wB[2 * i]),      x4.x, a0);
                        a1 = fmaf(__high2float(wB[2 * i]),     x4.y, a1);
                        a2 = fmaf(__low2float(wB[2 * i + 1]),  x4.z, a2);
                        a3 = fmaf(__high2float(wB[2 * i + 1]), x4.w, a3);
                    }
                }
                part0[kq][jl] = (a0 + a1) + (a2 + a3);
            }
        } else {
            if (t1 >= 0 && t1 < T_SEQ) {
                float a0 = 0.f, a1 = 0.f, a2 = 0.f, a3 = 0.f;
                {
                    const float4* rq = (const float4*)(&rbuf[t1 & 1][kq << 6]);
#pragma unroll
                    for (int i = 0; i < 16; i++) {
                        const float4 h4 = rq[i];
                        a0 = fmaf(__low2float(wA[2 * i]),      h4.x, a0);
                        a1 = fmaf(__high2float(wA[2 * i]),     h4.y, a1);
                        a2 = fmaf(__low2float(wA[2 * i + 1]),  h4.z, a2);
                        a3 = fmaf(__high2float(wA[2 * i + 1]), h4.w, a3);
                    }
                }
                if (t1 > 0) {
                    const float4* hq = (const float4*)(&hbuf1[t1 & 1][kq << 6]);
#pragma unroll
                    for (int i = 0; i < 16; i++) {
                        const float4 h4 = hq[i];
                        a0 = fmaf(__low2float(wB[2 * i]),      h4.x, a0);
                        a1 = fmaf(__high2float(wB[2 * i]),     h4.y, a1);
                        a2 = fmaf(__low2float(wB[2 * i + 1]),  h4.z, a2);
                        a3 = fmaf(__high2float(wB[2 * i + 1]), h4.w, a3);
                    }
                }
                part1[kq][jl] = (a0 + a1) + (a2 + a3);
            }
        }
        __syncthreads();   // B2
        // ---------------- epilogues ----------------
        if (!isL1) {
            if (tt < T_SEQ && tid < 64) {
                float v = bias;
#pragma unroll
                for (int q = 0; q < 8; q++) v += part0[q][tid];
                const float hv = tanhf(v);
                const __half hf = __float2half_rn(hv);
                unsigned short us; __builtin_memcpy(&us, &hf, 2);
                agent_store_u32(hp0_b + (((tt + 1) & 1) << 9) + (s << 6) + tid,
                                ((uint32_t)us << 16) | (uint32_t)(tt + 1));
                hbuf0[(tt + 1) & 1][(s << 6) + tid] = hbits2f(us);
                const uint32_t ru = (us & 0x8000u) ? 0u : (uint32_t)us;
                const uint32_t vlo = (uint32_t)__shfl((int)ru, (tid << 1) & 63, 64);
                const uint32_t vhi = (uint32_t)__shfl((int)ru, ((tid << 1) + 1) & 63, 64);
                if (tid < 32)
                    agent_store_u32(r0_b + (size_t)tt * 256 + (s << 5) + tid,
                                    (vhi << 16) | vlo);
                asm volatile("s_waitcnt vmcnt(0)" ::: "memory");
                if (tid == 0)
                    agent_store_u32(pr_b + s, (uint32_t)(tt + 1));
            }
        } else {
            if (t1 >= 0 && t1 < T_SEQ && tid < 576) {
                const int et = tid - 512;  // 0..63
                float v = bias;
#pragma unroll
                for (int q = 0; q < 8; q++) v += part1[q][et];
                const float hv = tanhf(v);
                const __half hf = __float2half_rn(hv);
                unsigned short us; __builtin_memcpy(&us, &hf, 2);
                agent_store_u32(hp1_b + (((t1 + 1) & 1) << 9) + (s << 6) + et,
                                ((uint32_t)us << 16) | (uint32_t)(t1 + 1));
                hbuf1[(t1 + 1) & 1][(s << 6) + et] = hbits2f(us);
                r1_b[(size_t)t1 * 512 + (s << 6) + et] =
                    (us & 0x8000u) ? (unsigned short)0 : us;
            }
        }
        // next iteration's B1 orders everything else
    }
}

// =====================================================================
// gemm2h: xp2 = relu1(fp16) @ Wih2^T + (bi+bh), fp16 out. (proven r10)
// =====================================================================
#define BM 64
#define BK 32
#define AS_STRIDE 68
#define BS_STRIDE 132

__global__ __launch_bounds__(256, 4) void gemm2h(
    const unsigned short* __restrict__ A,   // [M,512] fp16 bits
    const float* __restrict__ W,            // [128,512]
    const float* __restrict__ bi, const float* __restrict__ bh,
    unsigned short* __restrict__ C,         // [M,128] fp16 bits
    int M, int K)
{
    __shared__ float As[BK][AS_STRIDE];
    __shared__ float Bs[BK][BS_STRIDE];
    const int tid = threadIdx.x;
    const int tx = tid & 15, ty = tid >> 4;
    const int m0 = blockIdx.x * BM;
    const int lr = tid >> 3, lc = (tid & 7) << 2;

    float acc[4][8];
#pragma unroll
    for (int i = 0; i < 4; i++)
#pragma unroll
        for (int j = 0; j < 8; j++) acc[i][j] = 0.f;

    for (int k0 = 0; k0 < K; k0 += BK) {
#pragma unroll
        for (int p = 0; p < 2; p++) {
            const int m = p * 32 + lr;
            const uint2 u = *(const uint2*)(A + (size_t)(m0 + m) * K + k0 + lc);
            As[lc + 0][m] = hbits2f((unsigned short)(u.x & 0xffffu));
            As[lc + 1][m] = hbits2f((unsigned short)(u.x >> 16));
            As[lc + 2][m] = hbits2f((unsigned short)(u.y & 0xffffu));
            As[lc + 3][m] = hbits2f((unsigned short)(u.y >> 16));
        }
#pragma unroll
        for (int p = 0; p < 4; p++) {
            const int n = p * 32 + lr;
            const float4 b4 = *(const float4*)(W + (size_t)n * K + k0 + lc);
            Bs[lc + 0][n] = b4.x; Bs[lc + 1][n] = b4.y;
            Bs[lc + 2][n] = b4.z; Bs[lc + 3][n] = b4.w;
        }
        __syncthreads();
#pragma unroll
        for (int kk = 0; kk < BK; kk++) {
            const float4 a4  = *(const float4*)&As[kk][tx << 2];
            const float4 b4a = *(const float4*)&Bs[kk][ty << 3];
            const float4 b4b = *(const float4*)&Bs[kk][(ty << 3) + 4];
            const float a[4] = { a4.x, a4.y, a4.z, a4.w };
            const float b[8] = { b4a.x, b4a.y, b4a.z, b4a.w, b4b.x, b4b.y, b4b.z, b4b.w };
#pragma unroll
            for (int i = 0; i < 4; i++)
#pragma unroll
                for (int j = 0; j < 8; j++) acc[i][j] = fmaf(a[i], b[j], acc[i][j]);
        }
        __syncthreads();
    }
    const int nbase = ty << 3;
    const float4 bia = *(const float4*)(bi + nbase);
    const float4 bib = *(const float4*)(bi + nbase + 4);
    const float4 bha = *(const float4*)(bh + nbase);
    const float4 bhb = *(const float4*)(bh + nbase + 4);
    const float bt[8] = { bia.x + bha.x, bia.y + bha.y, bia.z + bha.z, bia.w + bha.w,
                          bib.x + bhb.x, bib.y + bhb.y, bib.z + bhb.z, bib.w + bhb.w };
#pragma unroll
    for (int i = 0; i < 4; i++) {
        const int row = m0 + (tx << 2) + i;
        uint32_t pk[4];
#pragma unroll
        for (int j = 0; j < 4; j++) {
            const __half hlo = __float2half_rn(acc[i][2 * j]     + bt[2 * j]);
            const __half hhi = __float2half_rn(acc[i][2 * j + 1] + bt[2 * j + 1]);
            unsigned short lo, hi;
            __builtin_memcpy(&lo, &hlo, 2); __builtin_memcpy(&hi, &hhi, 2);
            pk[j] = ((uint32_t)hi << 16) | lo;
        }
        *(uint4*)(C + (size_t)row * 128 + nbase) = make_uint4(pk[0], pk[1], pk[2], pk[3]);
    }
}

// =====================================================================
// Layer 2 recurrence (H=128), xp fp16. One WG/batch; LDS-only. (proven)
// =====================================================================
__global__ __launch_bounds__(256, 4) void rec128h(
    const float* __restrict__ Whh,          // [128,128]
    const unsigned short* __restrict__ xp,  // [NB,T,128] fp16 bits
    float* __restrict__ out,                // [NB,T,128]
    float* __restrict__ hn)                 // [NB,128]
{
    const int tid = threadIdx.x;
    const int b  = blockIdx.x;
    const int j  = tid & 127;
    const int kh = tid >> 7;

    __shared__ float hbuf[2][128];
    __shared__ float part[2][128];

    float w[64];
    {
        const float4* wp = (const float4*)(Whh + (size_t)j * 128 + (kh << 6));
#pragma unroll
        for (int i = 0; i < 16; i++) {
            const float4 v = wp[i];
            w[4 * i + 0] = v.x; w[4 * i + 1] = v.y;
            w[4 * i + 2] = v.z; w[4 * i + 3] = v.w;
        }
    }

    const unsigned short* xp_b = xp + (size_t)b * (T_SEQ * 128);
    float* out_b = out + (size_t)b * (T_SEQ * 128);

    float xpv = (tid < 128) ? hbits2f(xp_b[tid]) : 0.f;

    for (int t = 0; t < T_SEQ; t++) {
        float xpn = (tid < 128 && t + 1 < T_SEQ) ? hbits2f(xp_b[(t + 1) * 128 + tid]) : 0.f;

        float a0 = 0.f, a1 = 0.f, a2 = 0.f, a3 = 0.f;
        if (t > 0) {
            const float4* hq = (const float4*)(&hbuf[t & 1][kh << 6]);
#pragma unroll
            for (int i = 0; i < 16; i++) {
                const float4 h4 = hq[i];
                a0 = fmaf(w[4 * i + 0], h4.x, a0);
                a1 = fmaf(w[4 * i + 1], h4.y, a1);
                a2 = fmaf(w[4 * i + 2], h4.z, a2);
                a3 = fmaf(w[4 * i + 3], h4.w, a3);
            }
        }
        part[kh][j] = (a0 + a1) + (a2 + a3);
        __syncthreads();
        if (tid < 128) {
            const float v = part[0][tid] + part[1][tid] + xpv;
            const float h = tanhf(v);
            hbuf[(t + 1) & 1][tid] = h;
            out_b[t * 128 + tid] = h;
            if (t == T_SEQ - 1) hn[b * 128 + tid] = h;
        }
        __syncthreads();
        xpv = xpn;
    }
}

// =====================================================================
// Launch.  ws (bytes): r0w@0 16MB | r1h@16MB 16MB | xp2h@32MB 4MB |
//   hpk0@37,748,736 128KB | hpk1@37,879,808 128KB | prog0@38,010,880 1KB
// hpk0..prog0 are contiguous (263,168 B) and are zeroed every launch:
// the harness re-poisons d_ws, and prog0's >= poll must start from 0.
// =====================================================================
extern "C" void kernel_launch(void* const* d_in, const int* in_sizes, int n_in,
                              void* d_out, int out_size, void* d_ws, size_t ws_size,
                              hipStream_t stream)
{
    const float* x    = (const float*)d_in[0];
    const float* Wih0 = (const float*)d_in[1];
    const float* Whh0 = (const float*)d_in[2];
    const float* bih0 = (const float*)d_in[3];
    const float* bhh0 = (const float*)d_in[4];
    const float* Wih1 = (const float*)d_in[5];
    const float* Whh1 = (const float*)d_in[6];
    const float* bih1 = (const float*)d_in[7];
    const float* bhh1 = (const float*)d_in[8];
    const float* Wih2 = (const float*)d_in[9];
    const float* Whh2 = (const float*)d_in[10];
    const float* bih2 = (const float*)d_in[11];
    const float* bhh2 = (const float*)d_in[12];

    char* wsb = (char*)d_ws;
    uint32_t*       r0w  = (uint32_t*)wsb;
    unsigned short* r1h  = (unsigned short*)(wsb + 16777216);
    unsigned short* xp2h = (unsigned short*)(wsb + 33554432);
    uint32_t*       hpk0 = (uint32_t*)(wsb + 37748736);
    uint32_t*       hpk1 = (uint32_t*)(wsb + 37879808);
    uint32_t*       prog0= (uint32_t*)(wsb + 38010880);

    float* out = (float*)d_out;            // [32,512,128]
    float* hn  = out + NB * T_SEQ * 128;   // [1,32,128]

    const int M = NB * T_SEQ;  // 16384

    // Zero the sync region (hpk0|hpk1|prog0) before the fused kernel:
    // poison-robustness for prog0's >= poll and hpk's tag-equality polls.
    hipMemsetAsync(wsb + 37748736, 0, 263168, stream);

    rec512_both<<<256, 1024, 0, stream>>>(x, Wih0, Whh0, bih0, bhh0,
                                          Wih1, Whh1, bih1, bhh1,
                                          r0w, r1h, hpk0, hpk1, prog0);
    gemm2h<<<dim3(M / BM, 1), 256, 0, stream>>>(r1h, Wih2, bih2, bhh2, xp2h, M, 512);
    rec128h<<<NB, 256, 0, stream>>>(Whh2, xp2h, out, hn);
}

// Round 7
// 5433.377 us; speedup vs baseline: 1.5637x; 1.5637x over previous
//
#include <hip/hip_runtime.h>
#include <hip/hip_fp16.h>
#include <cstdint>
#include <cstddef>
#include <cstring>

#define T_SEQ 512
#define NB 32

__device__ __forceinline__ uint32_t agent_load_u32(const uint32_t* p) {
    return __hip_atomic_load(p, __ATOMIC_RELAXED, __HIP_MEMORY_SCOPE_AGENT);
}
__device__ __forceinline__ void agent_store_u32(uint32_t* p, uint32_t v) {
    __hip_atomic_store(p, v, __ATOMIC_RELAXED, __HIP_MEMORY_SCOPE_AGENT);
}
__device__ __forceinline__ float hbits2f(unsigned short us) {
    __half h; __builtin_memcpy(&h, &us, 2); return __half2float(h);
}
__device__ __forceinline__ uint32_t f2u2(float x, float y) {
    __half2 h = __floats2half2_rn(x, y);
    uint32_t u; __builtin_memcpy(&u, &h, 4); return u;
}
__device__ __forceinline__ __half2 u2h2(uint32_t u) {
    __half2 h; __builtin_memcpy(&h, &u, 4); return h;
}

// =====================================================================
// rec512_both: layers 0 AND 1 in ONE workgroup, wave-split + lockstep.
//   256 blocks (b = bid&31, s = bid>>5), 1024 threads:
//     tid   0..511 (waves 0-7) : layer-0 slice (b,s), weights in VGPRs
//     tid 512..1023 (waves 8-15): layer-1 slice (b,s), lag 2 (t1=tt-2),
//                                 weights in LDS (wlds)
//
// WHY LDS WEIGHTS FOR L1 (r5/r6 lesson): the backend pins VGPR at 64
// (8 waves/EU target) whenever LDS is small enough to permit 2 blocks/CU,
// and no source attribute overrides it — l1's 64 half2 weight regs then
// spill/remat every step (FETCH 11 GB, 8 ms). Fix: move l1's weights to
// LDS so (a) l1's register need drops to ~35, (b) the 148 KB LDS
// footprint caps occupancy at 1 block/CU, which the occupancy heuristic
// DOES respect. Bank math: wlds[k2][row] k2-major => a wave (64 rows,
// fixed k2) hits bank row%32 = 2 lanes/bank = free (m136). Activation
// reads are wave-wide same-address broadcasts (kq is wave-uniform).
//
// POISON ROBUSTNESS (r4 root cause): harness re-poisons d_ws; hpk polls
// are EQUALITY against small tags (poison-safe), but prog0's >= poll is
// not -> kernel_launch memsets hpk0|hpk1|prog0 (263168 B) to 0 first.
//
// Deadlock-freedom: every phase-A poll depends only on OTHER blocks
// having COMPLETED iteration <= tt-1 (hpk0 tag tt, prog0 >= tt, hpk1
// tag tt-2 are all produced at end of iteration tt-1); iteration 0 has
// no polls -> induction. Initial r0(0) staging is folded into tt=1.
// Lockstep backpressure makes tag-slot reuse safe (see r4 notes).
// =====================================================================
__global__ __launch_bounds__(1024)
__attribute__((amdgpu_waves_per_eu(4, 4)))
void rec512_both(
    const float* __restrict__ x,
    const float* __restrict__ Wih0, const float* __restrict__ Whh0,
    const float* __restrict__ bih0, const float* __restrict__ bhh0,
    const float* __restrict__ Wih1, const float* __restrict__ Whh1,
    const float* __restrict__ bih1, const float* __restrict__ bhh1,
    uint32_t* __restrict__ r0w,        // [NB][T][256] relu0 fp16 pairs
    unsigned short* __restrict__ r1h,  // [NB][T][512] fp16 bits
    uint32_t* __restrict__ hpk0, uint32_t* __restrict__ hpk1,
    uint32_t* __restrict__ prog0)      // [NB][8] layer-0 step counters
{
    __shared__ uint32_t wlds[512][64]; // 128 KB: l1 weights, fp16 pairs.
                                       // k2 0..255 = Wih1, 256..511 = Whh1;
                                       // wlds[k2][row], row 0..63 in slice.
    __shared__ float hbuf0[2][512];
    __shared__ float hbuf1[2][512];
    __shared__ float rbuf[2][512];     // relu0 staging for l1
    __shared__ float xbuf[2][128];     // x staging for l0
    __shared__ float part0[8][64];
    __shared__ float part1[8][64];

    const int tid  = threadIdx.x;
    const int b    = blockIdx.x & 31;
    const int s    = blockIdx.x >> 5;  // 0..7
    const bool isL1 = tid >= 512;
    const int lane = tid & 511;        // 0..511: poll-row within layer
    const int jl   = lane & 63;
    const int kq   = lane >> 6;        // 0..7, wave-uniform
    const int row  = (s << 6) + jl;
    const bool own = (kq == s);

    // ---- stage l1 weights into LDS (all 1024 threads, coalesced) ----
    {
#pragma unroll
        for (int i = 0; i < 16; i++) {
            const int g   = (i << 10) + tid;   // 0..16383 float4-index
            const int wr  = g >> 8;            // 0..63 row in slice
            const int rem = g & 255;
            const int mat = rem >> 7;          // 0: Wih1, 1: Whh1
            const int f4i = rem & 127;         // 0..127
            const float* srcm = mat ? Whh1 : Wih1;
            const float4 v = *(const float4*)(srcm +
                (size_t)((s << 6) + wr) * 512 + (f4i << 2));
            const int k2 = (mat << 8) + (f4i << 1);
            wlds[k2][wr]     = f2u2(v.x, v.y);
            wlds[k2 + 1][wr] = f2u2(v.z, v.w);
        }
    }

    // ---- l0 weights to VGPRs (fp16 pairs); l1 keeps none ----
    // l0: wA[0..31] = Whh0 row, 64 k  |  wB[0..7] = Wih0 row, 16 k
    __half2 wA[32], wB[8];
    if (!isL1) {
        const float4* p4 = (const float4*)(Whh0 + (size_t)row * 512 + (kq << 6));
#pragma unroll
        for (int i = 0; i < 16; i++) {
            const float4 v = p4[i];
            wA[2 * i]     = __floats2half2_rn(v.x, v.y);
            wA[2 * i + 1] = __floats2half2_rn(v.z, v.w);
        }
        const float4* q4 = (const float4*)(Wih0 + (size_t)row * 128 + (kq << 4));
#pragma unroll
        for (int i = 0; i < 4; i++) {
            const float4 v = q4[i];
            wB[2 * i]     = __floats2half2_rn(v.x, v.y);
            wB[2 * i + 1] = __floats2half2_rn(v.z, v.w);
        }
    }
    float bias = 0.f;
    if (tid < 64) {
        const int r = (s << 6) + tid; bias = bih0[r] + bhh0[r];
    } else if (tid >= 512 && tid < 576) {
        const int r = (s << 6) + (tid - 512); bias = bih1[r] + bhh1[r];
    }

    const float* x_b = x + (size_t)b * (T_SEQ * 128);
    uint32_t* r0_b = r0w + (size_t)b * (T_SEQ * 256);
    unsigned short* r1_b = r1h + (size_t)b * (T_SEQ * 512);
    uint32_t* hp0_b = hpk0 + (b << 10);
    uint32_t* hp1_b = hpk1 + (b << 10);
    uint32_t* pr_b  = prog0 + (b << 3);

    if (tid < 128) xbuf[0][tid] = x_b[tid];
    __syncthreads();   // wlds + xbuf[0] ready

    for (int tt = 0; tt < T_SEQ + 2; tt++) {
        const int t1 = tt - 2;
        // ---------------- phase A: polls + global prefetch ----------------
        float xn = 0.f;
        uint32_t rn = 0;
        if (!isL1) {
            if (tid < 128 && tt + 1 < T_SEQ) xn = x_b[(tt + 1) * 128 + tid];
            if (tt > 0 && tt < T_SEQ && !own) {
                const uint32_t wtag = (uint32_t)tt;
                uint32_t* sp = hp0_b + ((tt & 1) << 9) + lane;
                uint32_t v;
                do { v = agent_load_u32(sp); } while ((v & 0xffffu) != wtag);
                hbuf0[tt & 1][lane] = hbits2f((unsigned short)(v >> 16));
            }
        } else {
            // stagers: lanes 256..511 fetch r0(tt-1) for l1's step tt-1
            if (lane >= 256 && tt >= 1 && tt <= T_SEQ) {
                const int wl = lane - 256;   // 0..255
                const uint32_t need = (uint32_t)tt;
                const uint32_t* pp = pr_b + (wl >> 5);
                uint32_t pv;
                do { pv = agent_load_u32(pp); } while (pv < need);
                asm volatile("" ::: "memory");
                rn = agent_load_u32(r0_b + (size_t)(tt - 1) * 256 + wl);
            }
            if (t1 > 0 && t1 < T_SEQ && !own) {
                const uint32_t wtag = (uint32_t)t1;
                uint32_t* sp = hp1_b + ((t1 & 1) << 9) + lane;
                uint32_t v;
                do { v = agent_load_u32(sp); } while ((v & 0xffffu) != wtag);
                hbuf1[t1 & 1][lane] = hbits2f((unsigned short)(v >> 16));
            }
        }
        __syncthreads();   // B1
        // ---------------- post-B1 LDS writes ----------------
        if (!isL1) {
            if (tid < 128 && tt + 1 < T_SEQ) xbuf[(tt + 1) & 1][tid] = xn;
        } else if (lane >= 256 && tt >= 1 && tt <= T_SEQ) {
            const int wl = lane - 256;
            rbuf[(tt - 1) & 1][2 * wl]     = hbits2f((unsigned short)(rn & 0xffffu));
            rbuf[(tt - 1) & 1][2 * wl + 1] = hbits2f((unsigned short)(rn >> 16));
        }
        // ---------------- FMA ----------------
        if (!isL1) {
            if (tt < T_SEQ) {
                float a0 = 0.f, a1 = 0.f, a2 = 0.f, a3 = 0.f;
                if (tt > 0) {
                    const float4* hq = (const float4*)(&hbuf0[tt & 1][kq << 6]);
#pragma unroll
                    for (int i = 0; i < 16; i++) {
                        const float4 h4 = hq[i];
                        a0 = fmaf(__low2float(wA[2 * i]),      h4.x, a0);
                        a1 = fmaf(__high2float(wA[2 * i]),     h4.y, a1);
                        a2 = fmaf(__low2float(wA[2 * i + 1]),  h4.z, a2);
                        a3 = fmaf(__high2float(wA[2 * i + 1]), h4.w, a3);
                    }
                }
                {
                    const float4* xq = (const float4*)(&xbuf[tt & 1][kq << 4]);
#pragma unroll
                    for (int i = 0; i < 4; i++) {
                        const float4 x4 = xq[i];
                        a0 = fmaf(__low2float(wB[2 * i]),      x4.x, a0);
                        a1 = fmaf(__high2float(wB[2 * i]),     x4.y, a1);
                        a2 = fmaf(__low2float(wB[2 * i + 1]),  x4.z, a2);
                        a3 = fmaf(__high2float(wB[2 * i + 1]), x4.w, a3);
                    }
                }
                part0[kq][jl] = (a0 + a1) + (a2 + a3);
            }
        } else {
            if (t1 >= 0 && t1 < T_SEQ) {
                float a0 = 0.f, a1 = 0.f, a2 = 0.f, a3 = 0.f;
                const int kb = kq << 5;        // 32 k2 per kchunk
                {
                    const float4* rq = (const float4*)(&rbuf[t1 & 1][kq << 6]);
#pragma unroll
                    for (int i = 0; i < 16; i++) {
                        const float4 h4 = rq[i];
                        const __half2 wa = u2h2(wlds[kb + 2 * i][jl]);
                        const __half2 wb = u2h2(wlds[kb + 2 * i + 1][jl]);
                        a0 = fmaf(__low2float(wa),  h4.x, a0);
                        a1 = fmaf(__high2float(wa), h4.y, a1);
                        a2 = fmaf(__low2float(wb),  h4.z, a2);
                        a3 = fmaf(__high2float(wb), h4.w, a3);
                    }
                }
                if (t1 > 0) {
                    const float4* hq = (const float4*)(&hbuf1[t1 & 1][kq << 6]);
#pragma unroll
                    for (int i = 0; i < 16; i++) {
                        const float4 h4 = hq[i];
                        const __half2 wa = u2h2(wlds[256 + kb + 2 * i][jl]);
                        const __half2 wb = u2h2(wlds[256 + kb + 2 * i + 1][jl]);
                        a0 = fmaf(__low2float(wa),  h4.x, a0);
                        a1 = fmaf(__high2float(wa), h4.y, a1);
                        a2 = fmaf(__low2float(wb),  h4.z, a2);
                        a3 = fmaf(__high2float(wb), h4.w, a3);
                    }
                }
                part1[kq][jl] = (a0 + a1) + (a2 + a3);
            }
        }
        __syncthreads();   // B2
        // ---------------- epilogues ----------------
        if (!isL1) {
            if (tt < T_SEQ && tid < 64) {
                float v = bias;
#pragma unroll
                for (int q = 0; q < 8; q++) v += part0[q][tid];
                const float hv = tanhf(v);
                const __half hf = __float2half_rn(hv);
                unsigned short us; __builtin_memcpy(&us, &hf, 2);
                agent_store_u32(hp0_b + (((tt + 1) & 1) << 9) + (s << 6) + tid,
                                ((uint32_t)us << 16) | (uint32_t)(tt + 1));
                hbuf0[(tt + 1) & 1][(s << 6) + tid] = hbits2f(us);
                const uint32_t ru = (us & 0x8000u) ? 0u : (uint32_t)us;
                const uint32_t vlo = (uint32_t)__shfl((int)ru, (tid << 1) & 63, 64);
                const uint32_t vhi = (uint32_t)__shfl((int)ru, ((tid << 1) + 1) & 63, 64);
                if (tid < 32)
                    agent_store_u32(r0_b + (size_t)tt * 256 + (s << 5) + tid,
                                    (vhi << 16) | vlo);
                asm volatile("s_waitcnt vmcnt(0)" ::: "memory");
                if (tid == 0)
                    agent_store_u32(pr_b + s, (uint32_t)(tt + 1));
            }
        } else {
            if (t1 >= 0 && t1 < T_SEQ && tid < 576) {
                const int et = tid - 512;  // 0..63
                float v = bias;
#pragma unroll
                for (int q = 0; q < 8; q++) v += part1[q][et];
                const float hv = tanhf(v);
                const __half hf = __float2half_rn(hv);
                unsigned short us; __builtin_memcpy(&us, &hf, 2);
                agent_store_u32(hp1_b + (((t1 + 1) & 1) << 9) + (s << 6) + et,
                                ((uint32_t)us << 16) | (uint32_t)(t1 + 1));
                hbuf1[(t1 + 1) & 1][(s << 6) + et] = hbits2f(us);
                r1_b[(size_t)t1 * 512 + (s << 6) + et] =
                    (us & 0x8000u) ? (unsigned short)0 : us;
            }
        }
        // next iteration's B1 orders everything else
    }
}

// =====================================================================
// gemm2h: xp2 = relu1(fp16) @ Wih2^T + (bi+bh), fp16 out. (proven r10)
// =====================================================================
#define BM 64
#define BK 32
#define AS_STRIDE 68
#define BS_STRIDE 132

__global__ __launch_bounds__(256, 4) void gemm2h(
    const unsigned short* __restrict__ A,   // [M,512] fp16 bits
    const float* __restrict__ W,            // [128,512]
    const float* __restrict__ bi, const float* __restrict__ bh,
    unsigned short* __restrict__ C,         // [M,128] fp16 bits
    int M, int K)
{
    __shared__ float As[BK][AS_STRIDE];
    __shared__ float Bs[BK][BS_STRIDE];
    const int tid = threadIdx.x;
    const int tx = tid & 15, ty = tid >> 4;
    const int m0 = blockIdx.x * BM;
    const int lr = tid >> 3, lc = (tid & 7) << 2;

    float acc[4][8];
#pragma unroll
    for (int i = 0; i < 4; i++)
#pragma unroll
        for (int j = 0; j < 8; j++) acc[i][j] = 0.f;

    for (int k0 = 0; k0 < K; k0 += BK) {
#pragma unroll
        for (int p = 0; p < 2; p++) {
            const int m = p * 32 + lr;
            const uint2 u = *(const uint2*)(A + (size_t)(m0 + m) * K + k0 + lc);
            As[lc + 0][m] = hbits2f((unsigned short)(u.x & 0xffffu));
            As[lc + 1][m] = hbits2f((unsigned short)(u.x >> 16));
            As[lc + 2][m] = hbits2f((unsigned short)(u.y & 0xffffu));
            As[lc + 3][m] = hbits2f((unsigned short)(u.y >> 16));
        }
#pragma unroll
        for (int p = 0; p < 4; p++) {
            const int n = p * 32 + lr;
            const float4 b4 = *(const float4*)(W + (size_t)n * K + k0 + lc);
            Bs[lc + 0][n] = b4.x; Bs[lc + 1][n] = b4.y;
            Bs[lc + 2][n] = b4.z; Bs[lc + 3][n] = b4.w;
        }
        __syncthreads();
#pragma unroll
        for (int kk = 0; kk < BK; kk++) {
            const float4 a4  = *(const float4*)&As[kk][tx << 2];
            const float4 b4a = *(const float4*)&Bs[kk][ty << 3];
            const float4 b4b = *(const float4*)&Bs[kk][(ty << 3) + 4];
            const float a[4] = { a4.x, a4.y, a4.z, a4.w };
            const float b[8] = { b4a.x, b4a.y, b4a.z, b4a.w, b4b.x, b4b.y, b4b.z, b4b.w };
#pragma unroll
            for (int i = 0; i < 4; i++)
#pragma unroll
                for (int j = 0; j < 8; j++) acc[i][j] = fmaf(a[i], b[j], acc[i][j]);
        }
        __syncthreads();
    }
    const int nbase = ty << 3;
    const float4 bia = *(const float4*)(bi + nbase);
    const float4 bib = *(const float4*)(bi + nbase + 4);
    const float4 bha = *(const float4*)(bh + nbase);
    const float4 bhb = *(const float4*)(bh + nbase + 4);
    const float bt[8] = { bia.x + bha.x, bia.y + bha.y, bia.z + bha.z, bia.w + bha.w,
                          bib.x + bhb.x, bib.y + bhb.y, bib.z + bhb.z, bib.w + bhb.w };
#pragma unroll
    for (int i = 0; i < 4; i++) {
        const int row = m0 + (tx << 2) + i;
        uint32_t pk[4];
#pragma unroll
        for (int j = 0; j < 4; j++) {
            const __half hlo = __float2half_rn(acc[i][2 * j]     + bt[2 * j]);
            const __half hhi = __float2half_rn(acc[i][2 * j + 1] + bt[2 * j + 1]);
            unsigned short lo, hi;
            __builtin_memcpy(&lo, &hlo, 2); __builtin_memcpy(&hi, &hhi, 2);
            pk[j] = ((uint32_t)hi << 16) | lo;
        }
        *(uint4*)(C + (size_t)row * 128 + nbase) = make_uint4(pk[0], pk[1], pk[2], pk[3]);
    }
}

// =====================================================================
// Layer 2 recurrence (H=128), xp fp16. One WG/batch; LDS-only. (proven)
// =====================================================================
__global__ __launch_bounds__(256, 4) void rec128h(
    const float* __restrict__ Whh,          // [128,128]
    const unsigned short* __restrict__ xp,  // [NB,T,128] fp16 bits
    float* __restrict__ out,                // [NB,T,128]
    float* __restrict__ hn)                 // [NB,128]
{
    const int tid = threadIdx.x;
    const int b  = blockIdx.x;
    const int j  = tid & 127;
    const int kh = tid >> 7;

    __shared__ float hbuf[2][128];
    __shared__ float part[2][128];

    float w[64];
    {
        const float4* wp = (const float4*)(Whh + (size_t)j * 128 + (kh << 6));
#pragma unroll
        for (int i = 0; i < 16; i++) {
            const float4 v = wp[i];
            w[4 * i + 0] = v.x; w[4 * i + 1] = v.y;
            w[4 * i + 2] = v.z; w[4 * i + 3] = v.w;
        }
    }

    const unsigned short* xp_b = xp + (size_t)b * (T_SEQ * 128);
    float* out_b = out + (size_t)b * (T_SEQ * 128);

    float xpv = (tid < 128) ? hbits2f(xp_b[tid]) : 0.f;

    for (int t = 0; t < T_SEQ; t++) {
        float xpn = (tid < 128 && t + 1 < T_SEQ) ? hbits2f(xp_b[(t + 1) * 128 + tid]) : 0.f;

        float a0 = 0.f, a1 = 0.f, a2 = 0.f, a3 = 0.f;
        if (t > 0) {
            const float4* hq = (const float4*)(&hbuf[t & 1][kh << 6]);
#pragma unroll
            for (int i = 0; i < 16; i++) {
                const float4 h4 = hq[i];
                a0 = fmaf(w[4 * i + 0], h4.x, a0);
                a1 = fmaf(w[4 * i + 1], h4.y, a1);
                a2 = fmaf(w[4 * i + 2], h4.z, a2);
                a3 = fmaf(w[4 * i + 3], h4.w, a3);
            }
        }
        part[kh][j] = (a0 + a1) + (a2 + a3);
        __syncthreads();
        if (tid < 128) {
            const float v = part[0][tid] + part[1][tid] + xpv;
            const float h = tanhf(v);
            hbuf[(t + 1) & 1][tid] = h;
            out_b[t * 128 + tid] = h;
            if (t == T_SEQ - 1) hn[b * 128 + tid] = h;
        }
        __syncthreads();
        xpv = xpn;
    }
}

// =====================================================================
// Launch.  ws (bytes): r0w@0 16MB | r1h@16MB 16MB | xp2h@32MB 4MB |
//   hpk0@37,748,736 128KB | hpk1@37,879,808 128KB | prog0@38,010,880 1KB
// hpk0..prog0 are contiguous (263,168 B) and are zeroed every launch:
// the harness re-poisons d_ws, and prog0's >= poll must start from 0.
// =====================================================================
extern "C" void kernel_launch(void* const* d_in, const int* in_sizes, int n_in,
                              void* d_out, int out_size, void* d_ws, size_t ws_size,
                              hipStream_t stream)
{
    const float* x    = (const float*)d_in[0];
    const float* Wih0 = (const float*)d_in[1];
    const float* Whh0 = (const float*)d_in[2];
    const float* bih0 = (const float*)d_in[3];
    const float* bhh0 = (const float*)d_in[4];
    const float* Wih1 = (const float*)d_in[5];
    const float* Whh1 = (const float*)d_in[6];
    const float* bih1 = (const float*)d_in[7];
    const float* bhh1 = (const float*)d_in[8];
    const float* Wih2 = (const float*)d_in[9];
    const float* Whh2 = (const float*)d_in[10];
    const float* bih2 = (const float*)d_in[11];
    const float* bhh2 = (const float*)d_in[12];

    char* wsb = (char*)d_ws;
    uint32_t*       r0w  = (uint32_t*)wsb;
    unsigned short* r1h  = (unsigned short*)(wsb + 16777216);
    unsigned short* xp2h = (unsigned short*)(wsb + 33554432);
    uint32_t*       hpk0 = (uint32_t*)(wsb + 37748736);
    uint32_t*       hpk1 = (uint32_t*)(wsb + 37879808);
    uint32_t*       prog0= (uint32_t*)(wsb + 38010880);

    float* out = (float*)d_out;            // [32,512,128]
    float* hn  = out + NB * T_SEQ * 128;   // [1,32,128]

    const int M = NB * T_SEQ;  // 16384

    // Zero the sync region (hpk0|hpk1|prog0) before the fused kernel:
    // poison-robustness for prog0's >= poll and hpk's tag-equality polls.
    hipMemsetAsync(wsb + 37748736, 0, 263168, stream);

    rec512_both<<<256, 1024, 0, stream>>>(x, Wih0, Whh0, bih0, bhh0,
                                          Wih1, Whh1, bih1, bhh1,
                                          r0w, r1h, hpk0, hpk1, prog0);
    gemm2h<<<dim3(M / BM, 1), 256, 0, stream>>>(r1h, Wih2, bih2, bhh2, xp2h, M, 512);
    rec128h<<<NB, 256, 0, stream>>>(Whh2, xp2h, out, hn);
}

// Round 8
// 2191.024 us; speedup vs baseline: 3.8778x; 2.4798x over previous
//
#include <hip/hip_runtime.h>
#include <hip/hip_fp16.h>
#include <cstdint>
#include <cstddef>
#include <cstring>

#define T_SEQ 512
#define NB 32

__device__ __forceinline__ uint32_t agent_load_u32(const uint32_t* p) {
    return __hip_atomic_load(p, __ATOMIC_RELAXED, __HIP_MEMORY_SCOPE_AGENT);
}
__device__ __forceinline__ void agent_store_u32(uint32_t* p, uint32_t v) {
    __hip_atomic_store(p, v, __ATOMIC_RELAXED, __HIP_MEMORY_SCOPE_AGENT);
}
__device__ __forceinline__ float hbits2f(unsigned short us) {
    __half h; __builtin_memcpy(&h, &us, 2); return __half2float(h);
}
__device__ __forceinline__ uint32_t f2u2(float x, float y) {
    __half2 h = __floats2half2_rn(x, y);
    uint32_t u; __builtin_memcpy(&u, &h, 4); return u;
}
__device__ __forceinline__ __half2 u2h2(uint32_t u) {
    __half2 h; __builtin_memcpy(&h, &u, 4); return h;
}

// =====================================================================
// rec512_pair: 512 blocks x 1024 threads, TWO BLOCK TYPES, 2 blocks/CU.
//   blocks   0..255: layer-0 slice (b = bid&31, s = (bid&255)>>5)
//   blocks 256..511: layer-1 slice (same decomposition)
//
// WHY THIS SHAPE (r2..r7 lessons distilled):
//  * The allocator never exceeds 64 VGPR for these kernels; need > 64
//    => remat catastrophe (r5/r6: FETCH 11 GB). Need <= 60 => clean
//    (baseline l0/l1 = 60).
//  * VGPR 64 is the 32-wave boundary EXCLUSIVE (r2: 64 -> 1 blk/CU).
//    Two 16-wave blocks/CU need merged VGPR <= 60.
//  * Intra-block fusion (r7) couples both layers' poll latencies + LDS
//    weight streaming into one barrier critical path: 8.6 us/step. Bad.
//  => Separate blocks, decoupled barriers; lighten l1 only: Wih1 goes
//    to LDS (16 weight-half2 in regs instead of 32), l0 stays baseline.
//    Merged alloc ~= max(60, ~52) ~= 60 -> 2 blocks/CU co-resident.
//  * LDS padded to 77 KB/block: 2x77 fits 160 KB (2 blocks/CU), and the
//    LDS-capped 32-wave target keeps the VGPR budget at 64 (no remat).
//
// l0 -> l1 handoff (r7-proven protocol): l0 epilogue packs 64 relu
// outputs into 32 u32 words -> r0w[b][t][256], vmcnt(0) drain, then
// prog0[b][s] = t+1. l1 stagers keep a ring-4 rbufh pipeline: stage
// r0(0..2) in a prologue, then each iteration t poll prog0 >= t+4 and
// load r0(t+3) (poll runs on stager waves PARALLEL to the hpk1 poll
// waves, so the load latency hides under the h-exchange).
//
// POISON ROBUSTNESS (r4): harness re-poisons d_ws; hpk polls are tag-
// EQUALITY (poison-safe) but prog0's >= poll is not -> kernel_launch
// memsets hpk0|hpk1|prog0 (263168 B) to 0 on the stream first.
//
// Deadlock-freedom: l0 polls only hpk0 (peer l0 blocks, step <= t-1).
// l1 polls prog0 (l0 progress; l0 never waits on l1) and hpk1 (peer l1
// blocks, step <= t-1). Acyclic. Even fully serialized dispatch (l0
// prefix first — r2 proved in-order prefix on this HW) completes.
// =====================================================================
__global__ __launch_bounds__(1024, 2) void rec512_pair(
    const float* __restrict__ x,
    const float* __restrict__ Wih0, const float* __restrict__ Whh0,
    const float* __restrict__ bih0, const float* __restrict__ bhh0,
    const float* __restrict__ Wih1, const float* __restrict__ Whh1,
    const float* __restrict__ bih1, const float* __restrict__ bhh1,
    uint32_t* __restrict__ r0w,        // [NB][T][256] relu0 fp16 pairs
    unsigned short* __restrict__ r1h,  // [NB][T][512] fp16 bits
    uint32_t* __restrict__ hpk0, uint32_t* __restrict__ hpk1,
    uint32_t* __restrict__ prog0)      // [NB][8] layer-0 step counters
{
    __shared__ uint32_t wi_lds[256][64];  // 64 KB (l1 only): Wih1 fp16 pairs,
                                          // [k2][row ^ (k2&31)] XOR-swizzled
    __shared__ float    hbuf[2][512];     // h exchange (h0 for l0, h1 for l1)
    __shared__ uint32_t rbufh[4][256];    // 4 KB (l1 only): r0 pair ring
    __shared__ float    xbuf[2][128];     // 1 KB (l0 only)
    __shared__ float    part[16][64];     // 4 KB   => total 77 KB

    const int tid = threadIdx.x;
    const int bb  = blockIdx.x & 255;
    const int b   = bb & 31;
    const int s   = bb >> 5;           // 0..7
    const int jl  = tid & 63;
    const int kq  = tid >> 6;          // 0..15, wave-uniform
    const int row = (s << 6) + jl;
    const bool own = (kq == s);        // poll lanes tid<512 (kq 0..7)
    const int myrow = (s << 6) + tid;  // epilogue lanes tid<64

    const float* x_b = x + (size_t)b * (T_SEQ * 128);
    uint32_t* r0_b = r0w + (size_t)b * (T_SEQ * 256);
    unsigned short* r1_b = r1h + (size_t)b * (T_SEQ * 512);
    uint32_t* pr_b = prog0 + (b << 3);

    if (blockIdx.x < 256) {
        // ========================= layer 0 =========================
        // Baseline-proven geometry: wh[16]+wi[4] half2 = 20 weight regs.
        uint32_t* hp_b = hpk0 + (b << 10);
        __half2 wh[16], wi[4];
        {
            const float4* p4 = (const float4*)(Whh0 + (size_t)row * 512 + (kq << 5));
#pragma unroll
            for (int i = 0; i < 8; i++) {
                const float4 v = p4[i];
                wh[2 * i]     = __floats2half2_rn(v.x, v.y);
                wh[2 * i + 1] = __floats2half2_rn(v.z, v.w);
            }
            const float4* q4 = (const float4*)(Wih0 + (size_t)row * 128 + (kq << 3));
#pragma unroll
            for (int i = 0; i < 2; i++) {
                const float4 v = q4[i];
                wi[2 * i]     = __floats2half2_rn(v.x, v.y);
                wi[2 * i + 1] = __floats2half2_rn(v.z, v.w);
            }
        }
        float bias = 0.f;
        if (tid < 64) { const int r = (s << 6) + tid; bias = bih0[r] + bhh0[r]; }

        if (tid < 128) xbuf[0][tid] = x_b[tid];
        __syncthreads();

        for (int t = 0; t < T_SEQ; t++) {
            const int p = t & 1;
            float xn = 0.f;
            if (tid < 128 && t + 1 < T_SEQ) xn = x_b[(t + 1) * 128 + tid];

            if (t > 0 && tid < 512 && !own) {
                const uint32_t wtag = (uint32_t)t;
                uint32_t* sp = hp_b + (p << 9) + tid;
                uint32_t v;
                do { v = agent_load_u32(sp); } while ((v & 0xffffu) != wtag);
                hbuf[p][tid] = hbits2f((unsigned short)(v >> 16));
            }
            __syncthreads();   // B1
            if (tid < 128 && t + 1 < T_SEQ) xbuf[(t + 1) & 1][tid] = xn;

            float a0 = 0.f, a1 = 0.f, a2 = 0.f, a3 = 0.f;
            if (t > 0) {
                const float4* hq = (const float4*)(&hbuf[p][kq << 5]);
#pragma unroll
                for (int i = 0; i < 8; i++) {
                    const float4 h4 = hq[i];
                    a0 = fmaf(__low2float(wh[2 * i]),      h4.x, a0);
                    a1 = fmaf(__high2float(wh[2 * i]),     h4.y, a1);
                    a2 = fmaf(__low2float(wh[2 * i + 1]),  h4.z, a2);
                    a3 = fmaf(__high2float(wh[2 * i + 1]), h4.w, a3);
                }
            }
            {
                const float4* xq = (const float4*)(&xbuf[p][kq << 3]);
#pragma unroll
                for (int i = 0; i < 2; i++) {
                    const float4 x4 = xq[i];
                    a0 = fmaf(__low2float(wi[2 * i]),      x4.x, a0);
                    a1 = fmaf(__high2float(wi[2 * i]),     x4.y, a1);
                    a2 = fmaf(__low2float(wi[2 * i + 1]),  x4.z, a2);
                    a3 = fmaf(__high2float(wi[2 * i + 1]), x4.w, a3);
                }
            }
            part[kq][jl] = (a0 + a1) + (a2 + a3);
            __syncthreads();   // B2
            if (tid < 64) {
                const int p2 = (t + 1) & 1;
                float v = bias;
#pragma unroll
                for (int q = 0; q < 16; q++) v += part[q][tid];
                const float hv = tanhf(v);
                const __half hf = __float2half_rn(hv);
                unsigned short us; __builtin_memcpy(&us, &hf, 2);
                agent_store_u32(hp_b + (p2 << 9) + myrow,
                                ((uint32_t)us << 16) | (uint32_t)(t + 1));
                hbuf[p2][myrow] = hbits2f(us);
                const uint32_t ru = (us & 0x8000u) ? 0u : (uint32_t)us;
                const uint32_t vlo = (uint32_t)__shfl((int)ru, (tid << 1) & 63, 64);
                const uint32_t vhi = (uint32_t)__shfl((int)ru, ((tid << 1) + 1) & 63, 64);
                if (tid < 32)
                    agent_store_u32(r0_b + (size_t)t * 256 + (s << 5) + tid,
                                    (vhi << 16) | vlo);
                asm volatile("s_waitcnt vmcnt(0)" ::: "memory");
                if (tid == 0)
                    agent_store_u32(pr_b + s, (uint32_t)(t + 1));
            }
        }
    } else {
        // ========================= layer 1 =========================
        // Whh1 in regs (wh[16]); Wih1 in LDS (keeps VGPR need ~50).
        uint32_t* hp_b = hpk1 + (b << 10);
        __half2 wh[16];
        {
            const float4* p4 = (const float4*)(Whh1 + (size_t)row * 512 + (kq << 5));
#pragma unroll
            for (int i = 0; i < 8; i++) {
                const float4 v = p4[i];
                wh[2 * i]     = __floats2half2_rn(v.x, v.y);
                wh[2 * i + 1] = __floats2half2_rn(v.z, v.w);
            }
        }
        // Stage Wih1 slice -> wi_lds (coalesced global; XOR-swizzled LDS).
        {
#pragma unroll
            for (int i = 0; i < 8; i++) {
                const int g   = (i << 10) + tid;   // 0..8191 float4-index
                const int wr  = g >> 7;            // 0..63 row in slice
                const int f4i = g & 127;           // 0..127
                const float4 v = *(const float4*)(Wih1 +
                    (size_t)((s << 6) + wr) * 512 + (f4i << 2));
                const int k2 = f4i << 1;
                wi_lds[k2][wr ^ (k2 & 31)]           = f2u2(v.x, v.y);
                wi_lds[k2 + 1][wr ^ ((k2 + 1) & 31)] = f2u2(v.z, v.w);
            }
        }
        float bias = 0.f;
        if (tid < 64) { const int r = (s << 6) + tid; bias = bih1[r] + bhh1[r]; }

        const bool stager = (tid >= 512 && tid < 768);
        const int wl = tid - 512;          // 0..255 for stagers
        const uint32_t* pp = pr_b + (stager ? (wl >> 5) : 0);

        // Prologue: stage r0(0..2) into ring slots 0..2.
        if (stager) {
#pragma unroll
            for (int u = 0; u < 3; u++) {
                const uint32_t need = (uint32_t)(u + 1);
                uint32_t pv;
                do { pv = agent_load_u32(pp); } while (pv < need);
                asm volatile("" ::: "memory");
                rbufh[u][wl] = agent_load_u32(r0_b + (size_t)u * 256 + wl);
            }
        }
        __syncthreads();   // wi_lds + rbufh[0..2] ready

        for (int t = 0; t < T_SEQ; t++) {
            const int p = t & 1;
            uint32_t rn = 0;
            if (stager && t + 3 < T_SEQ) {
                const uint32_t need = (uint32_t)(t + 4);
                uint32_t pv;
                do { pv = agent_load_u32(pp); } while (pv < need);
                asm volatile("" ::: "memory");
                rn = agent_load_u32(r0_b + (size_t)(t + 3) * 256 + wl);
            }
            if (t > 0 && tid < 512 && !own) {
                const uint32_t wtag = (uint32_t)t;
                uint32_t* sp = hp_b + (p << 9) + tid;
                uint32_t v;
                do { v = agent_load_u32(sp); } while ((v & 0xffffu) != wtag);
                hbuf[p][tid] = hbits2f((unsigned short)(v >> 16));
            }
            __syncthreads();   // B1
            if (stager && t + 3 < T_SEQ) rbufh[(t + 3) & 3][wl] = rn;

            float a0 = 0.f, a1 = 0.f, a2 = 0.f, a3 = 0.f;
            {
                const int kb = kq << 4;   // 16 k2-pairs per 32-k chunk
#pragma unroll
                for (int i = 0; i < 16; i++) {
                    const int k2 = kb + i;
                    const __half2 wa = u2h2(wi_lds[k2][jl ^ (k2 & 31)]);
                    const __half2 rv = u2h2(rbufh[t & 3][k2]);
                    a0 = fmaf(__low2float(wa),  __low2float(rv),  a0);
                    a1 = fmaf(__high2float(wa), __high2float(rv), a1);
                }
            }
            if (t > 0) {
                const float4* hq = (const float4*)(&hbuf[p][kq << 5]);
#pragma unroll
                for (int i = 0; i < 8; i++) {
                    const float4 h4 = hq[i];
                    a0 = fmaf(__low2float(wh[2 * i]),      h4.x, a0);
                    a1 = fmaf(__high2float(wh[2 * i]),     h4.y, a1);
                    a2 = fmaf(__low2float(wh[2 * i + 1]),  h4.z, a2);
                    a3 = fmaf(__high2float(wh[2 * i + 1]), h4.w, a3);
                }
            }
            part[kq][jl] = (a0 + a1) + (a2 + a3);
            __syncthreads();   // B2
            if (tid < 64) {
                const int p2 = (t + 1) & 1;
                float v = bias;
#pragma unroll
                for (int q = 0; q < 16; q++) v += part[q][tid];
                const float hv = tanhf(v);
                const __half hf = __float2half_rn(hv);
                unsigned short us; __builtin_memcpy(&us, &hf, 2);
                agent_store_u32(hp_b + (p2 << 9) + myrow,
                                ((uint32_t)us << 16) | (uint32_t)(t + 1));
                hbuf[p2][myrow] = hbits2f(us);
                r1_b[(size_t)t * 512 + myrow] = (us & 0x8000u) ? (unsigned short)0 : us;
            }
        }
    }
}

// =====================================================================
// gemm2h: xp2 = relu1(fp16) @ Wih2^T + (bi+bh), fp16 out. (proven r10)
// =====================================================================
#define BM 64
#define BK 32
#define AS_STRIDE 68
#define BS_STRIDE 132

__global__ __launch_bounds__(256, 4) void gemm2h(
    const unsigned short* __restrict__ A,   // [M,512] fp16 bits
    const float* __restrict__ W,            // [128,512]
    const float* __restrict__ bi, const float* __restrict__ bh,
    unsigned short* __restrict__ C,         // [M,128] fp16 bits
    int M, int K)
{
    __shared__ float As[BK][AS_STRIDE];
    __shared__ float Bs[BK][BS_STRIDE];
    const int tid = threadIdx.x;
    const int tx = tid & 15, ty = tid >> 4;
    const int m0 = blockIdx.x * BM;
    const int lr = tid >> 3, lc = (tid & 7) << 2;

    float acc[4][8];
#pragma unroll
    for (int i = 0; i < 4; i++)
#pragma unroll
        for (int j = 0; j < 8; j++) acc[i][j] = 0.f;

    for (int k0 = 0; k0 < K; k0 += BK) {
#pragma unroll
        for (int p = 0; p < 2; p++) {
            const int m = p * 32 + lr;
            const uint2 u = *(const uint2*)(A + (size_t)(m0 + m) * K + k0 + lc);
            As[lc + 0][m] = hbits2f((unsigned short)(u.x & 0xffffu));
            As[lc + 1][m] = hbits2f((unsigned short)(u.x >> 16));
            As[lc + 2][m] = hbits2f((unsigned short)(u.y & 0xffffu));
            As[lc + 3][m] = hbits2f((unsigned short)(u.y >> 16));
        }
#pragma unroll
        for (int p = 0; p < 4; p++) {
            const int n = p * 32 + lr;
            const float4 b4 = *(const float4*)(W + (size_t)n * K + k0 + lc);
            Bs[lc + 0][n] = b4.x; Bs[lc + 1][n] = b4.y;
            Bs[lc + 2][n] = b4.z; Bs[lc + 3][n] = b4.w;
        }
        __syncthreads();
#pragma unroll
        for (int kk = 0; kk < BK; kk++) {
            const float4 a4  = *(const float4*)&As[kk][tx << 2];
            const float4 b4a = *(const float4*)&Bs[kk][ty << 3];
            const float4 b4b = *(const float4*)&Bs[kk][(ty << 3) + 4];
            const float a[4] = { a4.x, a4.y, a4.z, a4.w };
            const float b[8] = { b4a.x, b4a.y, b4a.z, b4a.w, b4b.x, b4b.y, b4b.z, b4b.w };
#pragma unroll
            for (int i = 0; i < 4; i++)
#pragma unroll
                for (int j = 0; j < 8; j++) acc[i][j] = fmaf(a[i], b[j], acc[i][j]);
        }
        __syncthreads();
    }
    const int nbase = ty << 3;
    const float4 bia = *(const float4*)(bi + nbase);
    const float4 bib = *(const float4*)(bi + nbase + 4);
    const float4 bha = *(const float4*)(bh + nbase);
    const float4 bhb = *(const float4*)(bh + nbase + 4);
    const float bt[8] = { bia.x + bha.x, bia.y + bha.y, bia.z + bha.z, bia.w + bha.w,
                          bib.x + bhb.x, bib.y + bhb.y, bib.z + bhb.z, bib.w + bhb.w };
#pragma unroll
    for (int i = 0; i < 4; i++) {
        const int row = m0 + (tx << 2) + i;
        uint32_t pk[4];
#pragma unroll
        for (int j = 0; j < 4; j++) {
            const __half hlo = __float2half_rn(acc[i][2 * j]     + bt[2 * j]);
            const __half hhi = __float2half_rn(acc[i][2 * j + 1] + bt[2 * j + 1]);
            unsigned short lo, hi;
            __builtin_memcpy(&lo, &hlo, 2); __builtin_memcpy(&hi, &hhi, 2);
            pk[j] = ((uint32_t)hi << 16) | lo;
        }
        *(uint4*)(C + (size_t)row * 128 + nbase) = make_uint4(pk[0], pk[1], pk[2], pk[3]);
    }
}

// =====================================================================
// Layer 2 recurrence (H=128), xp fp16. One WG/batch; LDS-only. (proven)
// =====================================================================
__global__ __launch_bounds__(256, 4) void rec128h(
    const float* __restrict__ Whh,          // [128,128]
    const unsigned short* __restrict__ xp,  // [NB,T,128] fp16 bits
    float* __restrict__ out,                // [NB,T,128]
    float* __restrict__ hn)                 // [NB,128]
{
    const int tid = threadIdx.x;
    const int b  = blockIdx.x;
    const int j  = tid & 127;
    const int kh = tid >> 7;

    __shared__ float hbuf[2][128];
    __shared__ float part[2][128];

    float w[64];
    {
        const float4* wp = (const float4*)(Whh + (size_t)j * 128 + (kh << 6));
#pragma unroll
        for (int i = 0; i < 16; i++) {
            const float4 v = wp[i];
            w[4 * i + 0] = v.x; w[4 * i + 1] = v.y;
            w[4 * i + 2] = v.z; w[4 * i + 3] = v.w;
        }
    }

    const unsigned short* xp_b = xp + (size_t)b * (T_SEQ * 128);
    float* out_b = out + (size_t)b * (T_SEQ * 128);

    float xpv = (tid < 128) ? hbits2f(xp_b[tid]) : 0.f;

    for (int t = 0; t < T_SEQ; t++) {
        float xpn = (tid < 128 && t + 1 < T_SEQ) ? hbits2f(xp_b[(t + 1) * 128 + tid]) : 0.f;

        float a0 = 0.f, a1 = 0.f, a2 = 0.f, a3 = 0.f;
        if (t > 0) {
            const float4* hq = (const float4*)(&hbuf[t & 1][kh << 6]);
#pragma unroll
            for (int i = 0; i < 16; i++) {
                const float4 h4 = hq[i];
                a0 = fmaf(w[4 * i + 0], h4.x, a0);
                a1 = fmaf(w[4 * i + 1], h4.y, a1);
                a2 = fmaf(w[4 * i + 2], h4.z, a2);
                a3 = fmaf(w[4 * i + 3], h4.w, a3);
            }
        }
        part[kh][j] = (a0 + a1) + (a2 + a3);
        __syncthreads();
        if (tid < 128) {
            const float v = part[0][tid] + part[1][tid] + xpv;
            const float h = tanhf(v);
            hbuf[(t + 1) & 1][tid] = h;
            out_b[t * 128 + tid] = h;
            if (t == T_SEQ - 1) hn[b * 128 + tid] = h;
        }
        __syncthreads();
        xpv = xpn;
    }
}

// =====================================================================
// Launch.  ws (bytes): r0w@0 16MB | r1h@16MB 16MB | xp2h@32MB 4MB |
//   hpk0@37,748,736 128KB | hpk1@37,879,808 128KB | prog0@38,010,880 1KB
// hpk0..prog0 are contiguous (263,168 B), zeroed every launch (poison).
// =====================================================================
extern "C" void kernel_launch(void* const* d_in, const int* in_sizes, int n_in,
                              void* d_out, int out_size, void* d_ws, size_t ws_size,
                              hipStream_t stream)
{
    const float* x    = (const float*)d_in[0];
    const float* Wih0 = (const float*)d_in[1];
    const float* Whh0 = (const float*)d_in[2];
    const float* bih0 = (const float*)d_in[3];
    const float* bhh0 = (const float*)d_in[4];
    const float* Wih1 = (const float*)d_in[5];
    const float* Whh1 = (const float*)d_in[6];
    const float* bih1 = (const float*)d_in[7];
    const float* bhh1 = (const float*)d_in[8];
    const float* Wih2 = (const float*)d_in[9];
    const float* Whh2 = (const float*)d_in[10];
    const float* bih2 = (const float*)d_in[11];
    const float* bhh2 = (const float*)d_in[12];

    char* wsb = (char*)d_ws;
    uint32_t*       r0w  = (uint32_t*)wsb;
    unsigned short* r1h  = (unsigned short*)(wsb + 16777216);
    unsigned short* xp2h = (unsigned short*)(wsb + 33554432);
    uint32_t*       hpk0 = (uint32_t*)(wsb + 37748736);
    uint32_t*       hpk1 = (uint32_t*)(wsb + 37879808);
    uint32_t*       prog0= (uint32_t*)(wsb + 38010880);

    float* out = (float*)d_out;            // [32,512,128]
    float* hn  = out + NB * T_SEQ * 128;   // [1,32,128]

    const int M = NB * T_SEQ;  // 16384

    // Zero the sync region (hpk0|hpk1|prog0): poison-robustness for the
    // prog0 >= poll and the hpk tag-equality polls.
    hipMemsetAsync(wsb + 37748736, 0, 263168, stream);

    rec512_pair<<<512, 1024, 0, stream>>>(x, Wih0, Whh0, bih0, bhh0,
                                          Wih1, Whh1, bih1, bhh1,
                                          r0w, r1h, hpk0, hpk1, prog0);
    gemm2h<<<dim3(M / BM, 1), 256, 0, stream>>>(r1h, Wih2, bih2, bhh2, xp2h, M, 512);
    rec128h<<<NB, 256, 0, stream>>>(Whh2, xp2h, out, hn);
}